// Round 1
// baseline (690.726 us; speedup 1.0000x reference)
//
#include <hip/hip_runtime.h>
#include <math.h>

// GraphCritic: GCNConv(x,W,b) with sym-norm + self-loops -> per-column lower
// median over nodes -> 3-layer tanh MLP -> scalar.
// Pipeline: degree count -> dinv -> CSR build (scan+fill) -> fp32 tiled GEMM
// (xw = x@W.T) -> per-node wave aggregation -> 4-pass radix-select median ->
// tiny MLP. All fp32 (bf16 MFMA would exceed the 3.5e-5 output threshold:
// median order-statistic spacing is ~6e-6).

#define F_DIM 128

__device__ __forceinline__ unsigned ordKey(float x) {
    unsigned u = __float_as_uint(x);
    return (u & 0x80000000u) ? ~u : (u | 0x80000000u);
}

// ---------------- init: zero accumulators, set select state ----------------
__global__ void k_init(int* __restrict__ indeg, int* __restrict__ cur,
                       int* __restrict__ hist, unsigned* __restrict__ prefix,
                       int* __restrict__ rank, int n) {
    int i = blockIdx.x * blockDim.x + threadIdx.x;
    int stride = gridDim.x * blockDim.x;
    int tot = n > 131072 ? n : 131072;
    for (int t = i; t < tot; t += stride) {
        if (t < n) { indeg[t] = 0; cur[t] = 0; }
        if (t < 131072) hist[t] = 0;           // 4 passes x 128 cols x 256 bins
        if (t < F_DIM) { prefix[t] = 0u; rank[t] = (n - 1) / 2; }
    }
}

// ---------------- degree count ----------------
__global__ void k_count(const int* __restrict__ dst, int E, int* __restrict__ indeg) {
    int i = blockIdx.x * blockDim.x + threadIdx.x;
    if (i < E) atomicAdd(&indeg[dst[i]], 1);
}

// deg = indeg + 1 (self loop); dinv = 1/sqrt(deg), computed in double then
// rounded (matches rsqrt to ~1 ulp)
__global__ void k_dinv(const int* __restrict__ indeg, float* __restrict__ dinv, int n) {
    int i = blockIdx.x * blockDim.x + threadIdx.x;
    if (i < n) dinv[i] = (float)(1.0 / sqrt((double)(indeg[i] + 1)));
}

// ---------------- exclusive scan of indeg -> offs (3 kernels) ----------------
__global__ void k_scanA(const int* __restrict__ indeg, int n, int* __restrict__ bsum) {
    const int base = blockIdx.x * 1024;
    int t = threadIdx.x;
    int idx = base + 4 * t;
    int s = 0;
    #pragma unroll
    for (int q = 0; q < 4; q++) if (idx + q < n) s += indeg[idx + q];
    #pragma unroll
    for (int off = 32; off; off >>= 1) s += __shfl_down(s, off, 64);
    __shared__ int wt[4];
    if ((t & 63) == 0) wt[t >> 6] = s;
    __syncthreads();
    if (t == 0) bsum[blockIdx.x] = wt[0] + wt[1] + wt[2] + wt[3];
}

__global__ void k_scanB(const int* __restrict__ bsum, int nb,
                        int* __restrict__ bbase, int* __restrict__ offs, int n) {
    if (threadIdx.x == 0) {
        int run = 0;
        for (int b = 0; b < nb; b++) { bbase[b] = run; run += bsum[b]; }
        offs[n] = run;   // == E
    }
}

__global__ void k_scanC(const int* __restrict__ indeg, int n,
                        const int* __restrict__ bbase, int* __restrict__ offs) {
    const int base = blockIdx.x * 1024;
    const int t = threadIdx.x, lane = t & 63, w = t >> 6;
    int idx = base + 4 * t;
    int v0 = 0, v1 = 0, v2 = 0, v3 = 0;
    if (idx + 0 < n) v0 = indeg[idx + 0];
    if (idx + 1 < n) v1 = indeg[idx + 1];
    if (idx + 2 < n) v2 = indeg[idx + 2];
    if (idx + 3 < n) v3 = indeg[idx + 3];
    int s = v0 + v1 + v2 + v3;
    int sc = s;
    #pragma unroll
    for (int off = 1; off < 64; off <<= 1) {
        int y = __shfl_up(sc, off, 64);
        if (lane >= off) sc += y;
    }
    __shared__ int wtot[4];
    if (lane == 63) wtot[w] = sc;
    __syncthreads();
    int wbase = 0;
    for (int ww = 0; ww < w; ww++) wbase += wtot[ww];
    int excl = bbase[blockIdx.x] + wbase + (sc - s);
    if (idx + 0 < n) offs[idx + 0] = excl; excl += v0;
    if (idx + 1 < n) offs[idx + 1] = excl; excl += v1;
    if (idx + 2 < n) offs[idx + 2] = excl; excl += v2;
    if (idx + 3 < n) offs[idx + 3] = excl;
}

// ---------------- CSR fill (src + precomputed edge weight) ----------------
__global__ void k_fill(const int* __restrict__ src, const int* __restrict__ dst, int E,
                       const float* __restrict__ dinv, const int* __restrict__ offs,
                       int* __restrict__ cur, int* __restrict__ adj, float* __restrict__ wgt) {
    int e = blockIdx.x * blockDim.x + threadIdx.x;
    if (e < E) {
        int s = src[e], d = dst[e];
        int pos = atomicAdd(&cur[d], 1);
        int o = offs[d] + pos;
        adj[o] = s;
        wgt[o] = dinv[s] * dinv[d];
    }
}

// ---------------- GEMM: xw[i,j] = sum_k x[i,k] * W[j,k]  (fp32 VALU) --------
// 128 rows/block, 256 threads, 16 rows x 4 cols per thread.
// W staged in LDS transposed (Wl[k][j]) in two 64-k halves; stride 132 keeps
// float4 reads 16B-aligned & conflict-free.
#define WL_S 132
__global__ __launch_bounds__(256) void k_gemm(const float* __restrict__ x,
                                              const float* __restrict__ W,
                                              float* __restrict__ xw, int n) {
    __shared__ float Wl[64 * WL_S];   // 33.8 KB
    __shared__ float xs[128 * 17];    // 8.7 KB
    const int t = threadIdx.x, tx = t & 31, ty = t >> 5;
    const int r0 = blockIdx.x * 128;
    float acc[16][4];
    #pragma unroll
    for (int r = 0; r < 16; r++)
        #pragma unroll
        for (int c = 0; c < 4; c++) acc[r][c] = 0.f;

    for (int kh = 0; kh < 128; kh += 64) {
        __syncthreads();   // protect Wl from previous half's readers
        // load W[j=0..127][k=kh..kh+63] -> Wl[k-kh][j]
        for (int m = t; m < 2048; m += 256) {        // 2048 float4s
            int j = (4 * m) >> 6;                    // 0..127
            int k = (4 * m) & 63;                    // 0..60 step 4
            float4 wv = *(const float4*)(W + j * 128 + kh + k);
            Wl[(k + 0) * WL_S + j] = wv.x;
            Wl[(k + 1) * WL_S + j] = wv.y;
            Wl[(k + 2) * WL_S + j] = wv.z;
            Wl[(k + 3) * WL_S + j] = wv.w;
        }
        for (int k0 = 0; k0 < 64; k0 += 16) {
            __syncthreads();  // also fences Wl writes on first iteration
            for (int m = t; m < 512; m += 256) {     // xs: 128 rows x 16 k
                int r = m >> 2, kk = (m & 3) << 2;
                int gr = r0 + r;
                float4 v = (gr < n) ? *(const float4*)(x + (size_t)gr * 128 + kh + k0 + kk)
                                    : make_float4(0.f, 0.f, 0.f, 0.f);
                xs[r * 17 + kk + 0] = v.x;
                xs[r * 17 + kk + 1] = v.y;
                xs[r * 17 + kk + 2] = v.z;
                xs[r * 17 + kk + 3] = v.w;
            }
            __syncthreads();
            #pragma unroll
            for (int kc = 0; kc < 16; kc++) {
                float4 wv = *(const float4*)(&Wl[(k0 + kc) * WL_S + 4 * tx]);
                #pragma unroll
                for (int rr = 0; rr < 16; rr++) {
                    float xv = xs[(ty * 16 + rr) * 17 + kc];
                    acc[rr][0] += xv * wv.x;
                    acc[rr][1] += xv * wv.y;
                    acc[rr][2] += xv * wv.z;
                    acc[rr][3] += xv * wv.w;
                }
            }
        }
    }
    #pragma unroll
    for (int rr = 0; rr < 16; rr++) {
        int gr = r0 + ty * 16 + rr;
        if (gr < n) {
            float4 o = make_float4(acc[rr][0], acc[rr][1], acc[rr][2], acc[rr][3]);
            *(float4*)(xw + (size_t)gr * 128 + 4 * tx) = o;
        }
    }
}

// ---------------- aggregation: one wave per destination node ----------------
__global__ __launch_bounds__(256) void k_agg(const float* __restrict__ xw,
                                             const int* __restrict__ offs,
                                             const int* __restrict__ adj,
                                             const float* __restrict__ wgt,
                                             const float* __restrict__ dinv,
                                             const float* __restrict__ conv_b,
                                             float* __restrict__ h, int n) {
    int d = (blockIdx.x << 2) + (threadIdx.x >> 6);
    if (d >= n) return;
    int lane = threadIdx.x & 63;
    const float2* xwv = (const float2*)xw;
    const int beg = offs[d], end = offs[d + 1];
    float dd = dinv[d];
    float sw = dd * dd;
    float2 a = xwv[(size_t)d * 64 + lane];
    float ax = sw * a.x, ay = sw * a.y;   // self-loop term
    int e = beg;
    for (; e + 4 <= end; e += 4) {
        int s0 = adj[e], s1 = adj[e + 1], s2 = adj[e + 2], s3 = adj[e + 3];
        float w0 = wgt[e], w1 = wgt[e + 1], w2 = wgt[e + 2], w3 = wgt[e + 3];
        float2 v0 = xwv[(size_t)s0 * 64 + lane];
        float2 v1 = xwv[(size_t)s1 * 64 + lane];
        float2 v2 = xwv[(size_t)s2 * 64 + lane];
        float2 v3 = xwv[(size_t)s3 * 64 + lane];
        ax += w0 * v0.x; ay += w0 * v0.y;
        ax += w1 * v1.x; ay += w1 * v1.y;
        ax += w2 * v2.x; ay += w2 * v2.y;
        ax += w3 * v3.x; ay += w3 * v3.y;
    }
    for (; e < end; e++) {
        int s = adj[e];
        float ww = wgt[e];
        float2 v = xwv[(size_t)s * 64 + lane];
        ax += ww * v.x; ay += ww * v.y;
    }
    float2 cb = ((const float2*)conv_b)[lane];
    float2 o; o.x = ax + cb.x; o.y = ay + cb.y;
    ((float2*)h)[(size_t)d * 64 + lane] = o;
}

// ---------------- median: 8-bit radix-select histogram pass ----------------
// LDS hist packs two columns per word (16-bit counts): cols j and j+64.
// Safe: <= ~200 elements per column per block << 65535.
__global__ __launch_bounds__(256) void k_hist(const float* __restrict__ h, int total4,
                                              const unsigned* __restrict__ prefix,
                                              int* __restrict__ ghist, int pass) {
    __shared__ unsigned lh[64 * 256];   // 64 KB
    for (int i = threadIdx.x; i < 16384; i += 256) lh[i] = 0u;
    __syncthreads();
    const int shiftLo = 24 - 8 * pass;
    const int stride = gridDim.x * blockDim.x;
    const float4* hv = (const float4*)h;
    for (int i = blockIdx.x * blockDim.x + threadIdx.x; i < total4; i += stride) {
        float4 v = hv[i];
        int jb = (i << 2) & 127;
        float vv[4] = {v.x, v.y, v.z, v.w};
        #pragma unroll
        for (int q = 0; q < 4; q++) {
            int j = jb + q;
            unsigned u = ordKey(vv[q]);
            bool ok = (pass == 0) || ((u >> (shiftLo + 8)) == prefix[j]);
            if (ok) {
                unsigned add = (j & 64) ? 65536u : 1u;
                atomicAdd(&lh[(j & 63) * 256 + ((u >> shiftLo) & 255)], add);
            }
        }
    }
    __syncthreads();
    for (int i = threadIdx.x; i < 16384; i += 256) {
        unsigned v = lh[i];
        unsigned lo = v & 0xFFFFu, hi = v >> 16;
        int c = i >> 8, bin = i & 255;
        if (lo) atomicAdd(&ghist[c * 256 + bin], (int)lo);
        if (hi) atomicAdd(&ghist[(c + 64) * 256 + bin], (int)hi);
    }
}

__global__ void k_select(const int* __restrict__ ghist, unsigned* __restrict__ prefix,
                         int* __restrict__ rank) {
    int j = threadIdx.x;
    if (j < 128) {
        const int* hj = ghist + j * 256;
        int r = rank[j];
        int cum = 0, b = 0;
        for (; b < 256; b++) {
            int c = hj[b];
            if (cum + c > r) break;
            cum += c;
        }
        rank[j] = r - cum;
        prefix[j] = (prefix[j] << 8) | (unsigned)b;
    }
}

// ---------------- MLP head ----------------
__global__ void k_mlp(const unsigned* __restrict__ prefix,
                      const float* __restrict__ w1, const float* __restrict__ b1,
                      const float* __restrict__ w2, const float* __restrict__ b2,
                      const float* __restrict__ w3, const float* __restrict__ b3,
                      float* __restrict__ out) {
    __shared__ float med[128], a1[64], a2[64];
    int t = threadIdx.x;
    if (t < 128) {
        unsigned u = prefix[t];
        unsigned bits = (u & 0x80000000u) ? (u & 0x7FFFFFFFu) : ~u;
        med[t] = __uint_as_float(bits);
    }
    __syncthreads();
    if (t < 64) {
        float acc = b1[t];
        for (int f = 0; f < 128; f++) acc += med[f] * w1[t * 128 + f];
        a1[t] = tanhf(acc);
    }
    __syncthreads();
    if (t < 64) {
        float acc = b2[t];
        for (int f = 0; f < 64; f++) acc += a1[f] * w2[t * 64 + f];
        a2[t] = tanhf(acc);
    }
    __syncthreads();
    if (t == 0) {
        float acc = b3[0];
        for (int f = 0; f < 64; f++) acc += a2[f] * w3[f];
        out[0] = acc;
    }
}

extern "C" void kernel_launch(void* const* d_in, const int* in_sizes, int n_in,
                              void* d_out, int out_size, void* d_ws, size_t ws_size,
                              hipStream_t stream) {
    const float* x      = (const float*)d_in[0];
    const int*   ei     = (const int*)d_in[1];
    const float* conv_W = (const float*)d_in[2];
    const float* conv_b = (const float*)d_in[3];
    const float* w1 = (const float*)d_in[4];
    const float* b1 = (const float*)d_in[5];
    const float* w2 = (const float*)d_in[6];
    const float* b2 = (const float*)d_in[7];
    const float* w3 = (const float*)d_in[8];
    const float* b3 = (const float*)d_in[9];

    const int N = in_sizes[0] / 128;
    const int E = in_sizes[1] / 2;
    const int* src = ei;
    const int* dst = ei + E;

    // workspace layout (~117 MB)
    char* p = (char*)d_ws;
    auto alloc = [&](size_t bytes) -> char* {
        char* q = p;
        p += (bytes + 255) & ~(size_t)255;
        return q;
    };
    float*    xw     = (float*)alloc((size_t)N * 128 * 4);
    float*    h      = (float*)alloc((size_t)N * 128 * 4);
    int*      adj    = (int*)alloc((size_t)E * 4);
    float*    wgt    = (float*)alloc((size_t)E * 4);
    float*    dinv   = (float*)alloc((size_t)N * 4);
    int*      indeg  = (int*)alloc((size_t)N * 4);
    int*      cur    = (int*)alloc((size_t)N * 4);
    int*      offs   = (int*)alloc((size_t)(N + 1) * 4);
    const int NB = (N + 1023) / 1024;
    int*      bsum   = (int*)alloc((size_t)NB * 4);
    int*      bbase  = (int*)alloc((size_t)NB * 4);
    int*      hist   = (int*)alloc((size_t)4 * 32768 * 4);
    unsigned* prefix = (unsigned*)alloc(128 * 4);
    int*      rank   = (int*)alloc(128 * 4);

    k_init<<<256, 256, 0, stream>>>(indeg, cur, hist, prefix, rank, N);
    k_count<<<(E + 255) / 256, 256, 0, stream>>>(dst, E, indeg);
    k_dinv<<<(N + 255) / 256, 256, 0, stream>>>(indeg, dinv, N);
    k_scanA<<<NB, 256, 0, stream>>>(indeg, N, bsum);
    k_scanB<<<1, 64, 0, stream>>>(bsum, NB, bbase, offs, N);
    k_scanC<<<NB, 256, 0, stream>>>(indeg, N, bbase, offs);
    k_fill<<<(E + 255) / 256, 256, 0, stream>>>(src, dst, E, dinv, offs, cur, adj, wgt);
    k_gemm<<<(N + 127) / 128, 256, 0, stream>>>(x, conv_W, xw, N);
    k_agg<<<(N + 3) / 4, 256, 0, stream>>>(xw, offs, adj, wgt, dinv, conv_b, h, N);
    const int total4 = N * 32;
    for (int pass = 0; pass < 4; pass++) {
        k_hist<<<512, 256, 0, stream>>>(h, total4, prefix, hist + pass * 32768, pass);
        k_select<<<1, 128, 0, stream>>>(hist + pass * 32768, prefix, rank);
    }
    k_mlp<<<1, 128, 0, stream>>>(prefix, w1, b1, w2, b2, w3, b3, (float*)d_out);
}

// Round 2
// 534.921 us; speedup vs baseline: 1.2913x; 1.2913x over previous
//
#include <hip/hip_runtime.h>
#include <math.h>

// GraphCritic: GCNConv (sym-norm + self-loops) -> per-column lower median ->
// tanh MLP -> scalar. All fp32 (bitwise-tight median: bf16/fp16 would blow
// the 3.5e-5 threshold).
// v2: median via 11-bit hist (no global atomics, partials + parallel select)
//     + candidate collect + per-column 21-bit radix select. wgt array dropped
//     (agg gathers dinv[src] from L2-resident table). gemm xs laid [k][row]
//     for ds_read_b128. dinv fused into scanA; scanB parallelized.

#define CAP 24576   // candidate capacity per column (expected few hundred)

__device__ __forceinline__ unsigned ordKey(float x) {
    unsigned u = __float_as_uint(x);
    return (u & 0x80000000u) ? ~u : (u | 0x80000000u);
}
__device__ __forceinline__ float keyToFloat(unsigned k) {
    unsigned bits = (k & 0x80000000u) ? (k & 0x7FFFFFFFu) : ~k;
    return __uint_as_float(bits);
}

// ---------------- init ----------------
__global__ void k_init(int* __restrict__ indeg, int* __restrict__ cur, int n) {
    int i = blockIdx.x * blockDim.x + threadIdx.x;
    int stride = gridDim.x * blockDim.x;
    for (int t = i; t < n; t += stride) { indeg[t] = 0; cur[t] = 0; }
}

// ---------------- degree count ----------------
__global__ void k_count(const int* __restrict__ dst, int E, int* __restrict__ indeg) {
    int i = blockIdx.x * blockDim.x + threadIdx.x;
    if (i < E) atomicAdd(&indeg[dst[i]], 1);
}

// ---------------- scan A: per-1024-block sums; fused dinv ----------------
__global__ void k_scanA(const int* __restrict__ indeg, int n, int* __restrict__ bsum,
                        float* __restrict__ dinv) {
    const int base = blockIdx.x * 1024;
    int t = threadIdx.x;
    int idx = base + 4 * t;
    int s = 0;
    #pragma unroll
    for (int q = 0; q < 4; q++)
        if (idx + q < n) {
            int d = indeg[idx + q];
            s += d;
            dinv[idx + q] = (float)(1.0 / sqrt((double)(d + 1)));
        }
    #pragma unroll
    for (int off = 32; off; off >>= 1) s += __shfl_down(s, off, 64);
    __shared__ int wt[4];
    if ((t & 63) == 0) wt[t >> 6] = s;
    __syncthreads();
    if (t == 0) bsum[blockIdx.x] = wt[0] + wt[1] + wt[2] + wt[3];
}

// ---------------- scan B: one wave, chunks of 64 ----------------
__global__ void k_scanB(const int* __restrict__ bsum, int nb,
                        int* __restrict__ bbase, int* __restrict__ offs, int n) {
    int lane = threadIdx.x & 63;
    int run = 0;
    for (int base = 0; base < nb; base += 64) {
        int v = (base + lane < nb) ? bsum[base + lane] : 0;
        int sc = v;
        #pragma unroll
        for (int off = 1; off < 64; off <<= 1) {
            int y = __shfl_up(sc, off, 64);
            if (lane >= off) sc += y;
        }
        if (base + lane < nb) bbase[base + lane] = run + sc - v;
        run += __shfl(sc, 63, 64);
    }
    if (lane == 0) offs[n] = run;
}

// ---------------- scan C: within-block exclusive ----------------
__global__ void k_scanC(const int* __restrict__ indeg, int n,
                        const int* __restrict__ bbase, int* __restrict__ offs) {
    const int base = blockIdx.x * 1024;
    const int t = threadIdx.x, lane = t & 63, w = t >> 6;
    int idx = base + 4 * t;
    int v0 = 0, v1 = 0, v2 = 0, v3 = 0;
    if (idx + 0 < n) v0 = indeg[idx + 0];
    if (idx + 1 < n) v1 = indeg[idx + 1];
    if (idx + 2 < n) v2 = indeg[idx + 2];
    if (idx + 3 < n) v3 = indeg[idx + 3];
    int s = v0 + v1 + v2 + v3;
    int sc = s;
    #pragma unroll
    for (int off = 1; off < 64; off <<= 1) {
        int y = __shfl_up(sc, off, 64);
        if (lane >= off) sc += y;
    }
    __shared__ int wtot[4];
    if (lane == 63) wtot[w] = sc;
    __syncthreads();
    int wbase = 0;
    for (int ww = 0; ww < w; ww++) wbase += wtot[ww];
    int excl = bbase[blockIdx.x] + wbase + (sc - s);
    if (idx + 0 < n) offs[idx + 0] = excl; excl += v0;
    if (idx + 1 < n) offs[idx + 1] = excl; excl += v1;
    if (idx + 2 < n) offs[idx + 2] = excl; excl += v2;
    if (idx + 3 < n) offs[idx + 3] = excl;
}

// ---------------- CSR fill: adj only (weights via dinv at agg time) -------
__global__ void k_fill(const int* __restrict__ src, const int* __restrict__ dst, int E,
                       const int* __restrict__ offs, int* __restrict__ cur,
                       int* __restrict__ adj) {
    int e = blockIdx.x * blockDim.x + threadIdx.x;
    if (e < E) {
        int d = dst[e];
        int pos = atomicAdd(&cur[d], 1);
        adj[offs[d] + pos] = src[e];
    }
}

// ---------------- GEMM: xw[i,j] = sum_k x[i,k] * W[j,k]  (fp32 VALU) ------
// 128 rows/block, 256 threads; thread = 16 rows x 4 cols.
// Wl[k][j] stride 132; xs[k][r] stride 132 -> fragment reads are b128.
#define WL_S 132
#define XS_S 132
__global__ __launch_bounds__(256) void k_gemm(const float* __restrict__ x,
                                              const float* __restrict__ W,
                                              float* __restrict__ xw, int n) {
    __shared__ float Wl[64 * WL_S];   // 33.8 KB
    __shared__ float xs[16 * XS_S];   // 8.4 KB
    const int t = threadIdx.x, tx = t & 31, ty = t >> 5;
    const int r0 = blockIdx.x * 128;
    float acc[16][4];
    #pragma unroll
    for (int r = 0; r < 16; r++)
        #pragma unroll
        for (int c = 0; c < 4; c++) acc[r][c] = 0.f;

    for (int kh = 0; kh < 128; kh += 64) {
        __syncthreads();
        for (int m = t; m < 2048; m += 256) {        // W[0..127][kh..kh+63]
            int j = m >> 4;
            int k = (4 * m) & 63;
            float4 wv = *(const float4*)(W + j * 128 + kh + k);
            Wl[(k + 0) * WL_S + j] = wv.x;
            Wl[(k + 1) * WL_S + j] = wv.y;
            Wl[(k + 2) * WL_S + j] = wv.z;
            Wl[(k + 3) * WL_S + j] = wv.w;
        }
        for (int k0 = 0; k0 < 64; k0 += 16) {
            __syncthreads();
            for (int m = t; m < 512; m += 256) {     // xs[k 0..15][r 0..127]
                int r = m >> 2, kk = (m & 3) << 2;
                int gr = r0 + r;
                float4 v = (gr < n) ? *(const float4*)(x + (size_t)gr * 128 + kh + k0 + kk)
                                    : make_float4(0.f, 0.f, 0.f, 0.f);
                xs[(kk + 0) * XS_S + r] = v.x;
                xs[(kk + 1) * XS_S + r] = v.y;
                xs[(kk + 2) * XS_S + r] = v.z;
                xs[(kk + 3) * XS_S + r] = v.w;
            }
            __syncthreads();
            #pragma unroll
            for (int kc = 0; kc < 16; kc++) {
                float4 wv = *(const float4*)(&Wl[(k0 + kc) * WL_S + 4 * tx]);
                const float4* xr = (const float4*)(&xs[kc * XS_S + ty * 16]);
                float xv[16];
                *(float4*)(&xv[0])  = xr[0];
                *(float4*)(&xv[4])  = xr[1];
                *(float4*)(&xv[8])  = xr[2];
                *(float4*)(&xv[12]) = xr[3];
                #pragma unroll
                for (int rr = 0; rr < 16; rr++) {
                    acc[rr][0] += xv[rr] * wv.x;
                    acc[rr][1] += xv[rr] * wv.y;
                    acc[rr][2] += xv[rr] * wv.z;
                    acc[rr][3] += xv[rr] * wv.w;
                }
            }
        }
    }
    #pragma unroll
    for (int rr = 0; rr < 16; rr++) {
        int gr = r0 + ty * 16 + rr;
        if (gr < n) {
            float4 o = make_float4(acc[rr][0], acc[rr][1], acc[rr][2], acc[rr][3]);
            *(float4*)(xw + (size_t)gr * 128 + 4 * tx) = o;
        }
    }
}

// ---------------- aggregation: one wave per destination node --------------
__global__ __launch_bounds__(256) void k_agg(const float* __restrict__ xw,
                                             const int* __restrict__ offs,
                                             const int* __restrict__ adj,
                                             const float* __restrict__ dinv,
                                             const float* __restrict__ conv_b,
                                             float* __restrict__ h, int n) {
    int d = (blockIdx.x << 2) + (threadIdx.x >> 6);
    if (d >= n) return;
    int lane = threadIdx.x & 63;
    const float2* xwv = (const float2*)xw;
    const int beg = offs[d], end = offs[d + 1];
    float dd = dinv[d];
    float2 a = xwv[(size_t)d * 64 + lane];
    float ax = dd * dd * a.x, ay = dd * dd * a.y;   // self-loop
    int e = beg;
    for (; e + 4 <= end; e += 4) {
        int s0 = adj[e], s1 = adj[e + 1], s2 = adj[e + 2], s3 = adj[e + 3];
        float w0 = dd * dinv[s0], w1 = dd * dinv[s1];
        float w2 = dd * dinv[s2], w3 = dd * dinv[s3];
        float2 v0 = xwv[(size_t)s0 * 64 + lane];
        float2 v1 = xwv[(size_t)s1 * 64 + lane];
        float2 v2 = xwv[(size_t)s2 * 64 + lane];
        float2 v3 = xwv[(size_t)s3 * 64 + lane];
        ax += w0 * v0.x; ay += w0 * v0.y;
        ax += w1 * v1.x; ay += w1 * v1.y;
        ax += w2 * v2.x; ay += w2 * v2.y;
        ax += w3 * v3.x; ay += w3 * v3.y;
    }
    for (; e < end; e++) {
        int s = adj[e];
        float ww = dd * dinv[s];
        float2 v = xwv[(size_t)s * 64 + lane];
        ax += ww * v.x; ay += ww * v.y;
    }
    float2 cb = ((const float2*)conv_b)[lane];
    float2 o; o.x = ax + cb.x; o.y = ay + cb.y;
    ((float2*)h)[(size_t)d * 64 + lane] = o;
}

// ---------------- median phase 1: 11-bit histogram, partials --------------
// Block (g,s): cols [16g,16g+16), rows slice s of 64. LDS: 8 packed col-pairs
// (j, j+8) x 2048 bins x 16-bit counts = 64 KB. Flush = plain coalesced write.
__global__ __launch_bounds__(256) void k_hist11(const float* __restrict__ h, int n,
                                                unsigned* __restrict__ part) {
    __shared__ unsigned lh[8 * 2048];   // 64 KB
    for (int i = threadIdx.x; i < 16384; i += 256) lh[i] = 0u;
    __syncthreads();
    const int g = blockIdx.x >> 6;      // col group 0..7
    const int s = blockIdx.x & 63;      // row slice 0..63
    const int rowsPer = (n + 63) >> 6;
    const int rowBeg = s * rowsPer;
    const int rowEnd = min(rowBeg + rowsPer, n);
    const float* hp = h + (size_t)g * 16;
    for (int r = rowBeg + threadIdx.x; r < rowEnd; r += 256) {
        const float4* rp = (const float4*)(hp + (size_t)r * 128);
        float4 q0 = rp[0], q1 = rp[1], q2 = rp[2], q3 = rp[3];
        float vv[16] = {q0.x,q0.y,q0.z,q0.w, q1.x,q1.y,q1.z,q1.w,
                        q2.x,q2.y,q2.z,q2.w, q3.x,q3.y,q3.z,q3.w};
        #pragma unroll
        for (int c = 0; c < 16; c++) {
            unsigned u = ordKey(vv[c]);
            unsigned add = (c & 8) ? 65536u : 1u;
            atomicAdd(&lh[(c & 7) * 2048 + (u >> 21)], add);
        }
    }
    __syncthreads();
    int4* dst = (int4*)(part + (size_t)blockIdx.x * 16384);
    const int4* srcp = (const int4*)lh;
    for (int i = threadIdx.x; i < 4096; i += 256) dst[i] = srcp[i];
}

// ---------------- median phase 2: reduce partials + pick bin --------------
// Block pc handles packed pair: cols cLo = 16*(pc>>3) + (pc&7), cHi = cLo+8.
__global__ __launch_bounds__(256) void k_sel11(const unsigned* __restrict__ part,
                                               int rank,
                                               int* __restrict__ selBin,
                                               int* __restrict__ selRank,
                                               int* __restrict__ candCnt) {
    __shared__ int histLo[2048], histHi[2048];
    const int g = blockIdx.x >> 3, j7 = blockIdx.x & 7;
    const int t = threadIdx.x;
    const unsigned* base = part + (size_t)g * 64 * 16384 + j7 * 2048;
    #pragma unroll
    for (int k = 0; k < 8; k++) {
        int bin = t + 256 * k;
        int lo = 0, hi = 0;
        for (int s = 0; s < 64; s++) {
            unsigned w = base[(size_t)s * 16384 + bin];
            lo += (int)(w & 0xFFFFu);
            hi += (int)(w >> 16);
        }
        histLo[bin] = lo;
        histHi[bin] = hi;
    }
    __syncthreads();
    if (t < 64) {
        const int lane = t;
        #pragma unroll
        for (int which = 0; which < 2; which++) {
            const int* hh = which ? histHi : histLo;
            int ps = 0;
            for (int b = lane * 32; b < lane * 32 + 32; b++) ps += hh[b];
            int sc = ps;
            #pragma unroll
            for (int off = 1; off < 64; off <<= 1) {
                int y = __shfl_up(sc, off, 64);
                if (lane >= off) sc += y;
            }
            int excl = sc - ps;
            if (excl <= rank && rank < sc) {
                int rem = rank - excl, b = lane * 32;
                for (;; b++) {
                    int c = hh[b];
                    if (rem < c) break;
                    rem -= c;
                }
                int col = g * 16 + j7 + (which ? 8 : 0);
                selBin[col] = b;
                selRank[col] = rem;
                candCnt[col] = 0;
            }
        }
    }
}

// ---------------- median phase 3: collect candidates ----------------------
__global__ __launch_bounds__(256) void k_collect(const float* __restrict__ h, int total4,
                                                 const int* __restrict__ selBin,
                                                 int* __restrict__ candCnt,
                                                 float* __restrict__ cand) {
    const int stride = gridDim.x * blockDim.x;
    const float4* hv = (const float4*)h;
    for (int i = blockIdx.x * blockDim.x + threadIdx.x; i < total4; i += stride) {
        float4 v = hv[i];
        int jb = (i << 2) & 127;
        float vv[4] = {v.x, v.y, v.z, v.w};
        #pragma unroll
        for (int q = 0; q < 4; q++) {
            int j = jb + q;
            unsigned u = ordKey(vv[q]);
            if ((int)(u >> 21) == selBin[j]) {
                int pos = atomicAdd(&candCnt[j], 1);
                if (pos < CAP) cand[(size_t)j * CAP + pos] = vv[q];
            }
        }
    }
}

// ---------------- median phase 4: 21-bit radix select (3 x 7 bits) --------
__global__ __launch_bounds__(256) void k_final(const float* __restrict__ cand,
                                               const int* __restrict__ candCnt,
                                               const int* __restrict__ selBin,
                                               const int* __restrict__ selRank,
                                               float* __restrict__ med) {
    __shared__ int hist[128];
    __shared__ unsigned sPrefix;
    __shared__ int sRank;
    const int c = blockIdx.x, t = threadIdx.x;
    const int cnt = min(candCnt[c], CAP);
    const float* cp = cand + (size_t)c * CAP;
    if (t == 0) {
        sPrefix = ((unsigned)selBin[c]) << 21;
        sRank = selRank[c];
    }
    __syncthreads();
    #pragma unroll
    for (int round = 0; round < 3; round++) {
        const int sh = 14 - 7 * round;
        if (t < 128) hist[t] = 0;
        __syncthreads();
        unsigned pref = sPrefix;
        int shHi = sh + 7;
        for (int i = t; i < cnt; i += 256) {
            unsigned u = ordKey(cp[i]);
            if ((u >> shHi) == (pref >> shHi))
                atomicAdd(&hist[(u >> sh) & 127], 1);
        }
        __syncthreads();
        if (t < 64) {
            int h0 = hist[2 * t], h1 = hist[2 * t + 1];
            int ps = h0 + h1, sc = ps;
            #pragma unroll
            for (int off = 1; off < 64; off <<= 1) {
                int y = __shfl_up(sc, off, 64);
                if (t >= off) sc += y;
            }
            int excl = sc - ps;
            int r = sRank;
            if (excl <= r && r < sc) {
                int bin, rem = r - excl;
                if (rem < h0) bin = 2 * t;
                else { bin = 2 * t + 1; rem -= h0; }
                sPrefix = pref | ((unsigned)bin << sh);
                sRank = rem;
            }
        }
        __syncthreads();
    }
    if (t == 0) med[c] = keyToFloat(sPrefix);
}

// ---------------- MLP head ----------------
__global__ void k_mlp(const float* __restrict__ med,
                      const float* __restrict__ w1, const float* __restrict__ b1,
                      const float* __restrict__ w2, const float* __restrict__ b2,
                      const float* __restrict__ w3, const float* __restrict__ b3,
                      float* __restrict__ out) {
    __shared__ float m[128], a1[64], a2[64];
    int t = threadIdx.x;
    if (t < 128) m[t] = med[t];
    __syncthreads();
    if (t < 64) {
        float acc = b1[t];
        for (int f = 0; f < 128; f++) acc += m[f] * w1[t * 128 + f];
        a1[t] = tanhf(acc);
    }
    __syncthreads();
    if (t < 64) {
        float acc = b2[t];
        for (int f = 0; f < 64; f++) acc += a1[f] * w2[t * 64 + f];
        a2[t] = tanhf(acc);
    }
    __syncthreads();
    if (t == 0) {
        float acc = b3[0];
        for (int f = 0; f < 64; f++) acc += a2[f] * w3[f];
        out[0] = acc;
    }
}

extern "C" void kernel_launch(void* const* d_in, const int* in_sizes, int n_in,
                              void* d_out, int out_size, void* d_ws, size_t ws_size,
                              hipStream_t stream) {
    const float* x      = (const float*)d_in[0];
    const int*   ei     = (const int*)d_in[1];
    const float* conv_W = (const float*)d_in[2];
    const float* conv_b = (const float*)d_in[3];
    const float* w1 = (const float*)d_in[4];
    const float* b1 = (const float*)d_in[5];
    const float* w2 = (const float*)d_in[6];
    const float* b2 = (const float*)d_in[7];
    const float* w3 = (const float*)d_in[8];
    const float* b3 = (const float*)d_in[9];

    const int N = in_sizes[0] / 128;
    const int E = in_sizes[1] / 2;
    const int* src = ei;
    const int* dst = ei + E;

    char* p = (char*)d_ws;
    auto alloc = [&](size_t bytes) -> char* {
        char* q = p;
        p += (bytes + 255) & ~(size_t)255;
        return q;
    };
    float* xw    = (float*)alloc((size_t)N * 128 * 4);   // dead after k_agg:
    // overlay: part (512*16384*4 = 33.55 MB) + cand (128*CAP*4 = 12.6 MB)
    unsigned* part = (unsigned*)xw;
    float*    cand = (float*)((char*)xw + (size_t)512 * 16384 * 4);
    float* h     = (float*)alloc((size_t)N * 128 * 4);
    int*   adj   = (int*)alloc((size_t)E * 4);
    float* dinv  = (float*)alloc((size_t)N * 4);
    int*   indeg = (int*)alloc((size_t)N * 4);
    int*   cur   = (int*)alloc((size_t)N * 4);
    int*   offs  = (int*)alloc((size_t)(N + 1) * 4);
    const int NB = (N + 1023) / 1024;
    int*   bsum    = (int*)alloc((size_t)NB * 4);
    int*   bbase   = (int*)alloc((size_t)NB * 4);
    int*   selBin  = (int*)alloc(128 * 4);
    int*   selRank = (int*)alloc(128 * 4);
    int*   candCnt = (int*)alloc(128 * 4);
    float* med     = (float*)alloc(128 * 4);

    k_init<<<128, 256, 0, stream>>>(indeg, cur, N);
    k_count<<<(E + 255) / 256, 256, 0, stream>>>(dst, E, indeg);
    k_scanA<<<NB, 256, 0, stream>>>(indeg, N, bsum, dinv);
    k_scanB<<<1, 64, 0, stream>>>(bsum, NB, bbase, offs, N);
    k_scanC<<<NB, 256, 0, stream>>>(indeg, N, bbase, offs);
    k_fill<<<(E + 255) / 256, 256, 0, stream>>>(src, dst, E, offs, cur, adj);
    k_gemm<<<(N + 127) / 128, 256, 0, stream>>>(x, conv_W, xw, N);
    k_agg<<<(N + 3) / 4, 256, 0, stream>>>(xw, offs, adj, dinv, conv_b, h, N);
    k_hist11<<<512, 256, 0, stream>>>(h, N, part);
    k_sel11<<<64, 256, 0, stream>>>(part, (N - 1) / 2, selBin, selRank, candCnt);
    k_collect<<<512, 256, 0, stream>>>(h, N * 32, selBin, candCnt, cand);
    k_final<<<128, 256, 0, stream>>>(cand, candCnt, selBin, selRank, med);
    k_mlp<<<1, 128, 0, stream>>>(med, w1, b1, w2, b2, w3, b3, (float*)d_out);
}